// Round 2
// baseline (726.169 us; speedup 1.0000x reference)
//
#include <hip/hip_runtime.h>

// SimpleGRU scan: B=2048 seqs, T=2048 steps, H=32, O=2, fp32.
// Round-2 mapping: ONE batch per wave (2048 waves = 2 waves/SIMD for TLP).
// Lane l = (j = l&31, half = l>>5). Lane holds w_hh rows {j, 32+j, 64+j},
// cols [16*half, 16*half+16) as 12 explicit float4 vars (48 VGPRs — round 1's
// private arrays got demoted, VGPR_Count=68 proved it). Per step: each lane
// does 3 half-dots (48 FMA, 2 chains/gate), combines via __shfl_xor(32),
// activations redundantly in both halves (bitwise-identical), h_j kept in
// LDS for broadcast reads. Single wave per block -> wave_barrier only.

__device__ __forceinline__ float sigmoid_fast(float s) {
    float e = __builtin_amdgcn_exp2f(s * -1.44269504088896340736f);
    return __builtin_amdgcn_rcpf(1.0f + e);
}

__device__ __forceinline__ float tanh_fast(float u) {
    // tanh(u) = 1 - 2/(1+exp2(u*2*log2e)); robust in fp32 at both tails
    float e = __builtin_amdgcn_exp2f(u * 2.88539008177792681472f);
    float r = __builtin_amdgcn_rcpf(1.0f + e);
    return fmaf(-2.0f, r, 1.0f);
}

__global__ __launch_bounds__(64, 2)
void gru_scan_kernel(const float* __restrict__ x,      // [B,T]
                     const float* __restrict__ w_ih,   // [96,1]
                     const float* __restrict__ w_hh,   // [96,32]
                     const float* __restrict__ b_ih,   // [96]
                     const float* __restrict__ b_hh,   // [96]
                     const float* __restrict__ head_w, // [2,32]
                     const float* __restrict__ head_b, // [2]
                     float* __restrict__ out,          // [B,2]
                     int T)
{
    const int l    = (int)threadIdx.x;
    const int j    = l & 31;
    const int half = l >> 5;
    const int b    = (int)blockIdx.x;

    __shared__ __align__(16) float h_s[32];
    __shared__ __align__(16) float x_s[2][64];

    // ---- per-lane weights: explicit float4s, forced register residency ----
    const float* wbase = w_hh + half * 16;
    const float4* wrp = (const float4*)(wbase + (     j) * 32);
    const float4* wzp = (const float4*)(wbase + (32 + j) * 32);
    const float4* wnp = (const float4*)(wbase + (64 + j) * 32);
    const float4 wr0 = wrp[0], wr1 = wrp[1], wr2 = wrp[2], wr3 = wrp[3];
    const float4 wz0 = wzp[0], wz1 = wzp[1], wz2 = wzp[2], wz3 = wzp[3];
    const float4 wn0 = wnp[0], wn1 = wnp[1], wn2 = wnp[2], wn3 = wnp[3];

    const float wihr = w_ih[j];
    const float wihz = w_ih[32 + j];
    const float wihn = w_ih[64 + j];
    const float br   = b_ih[j]      + b_hh[j];
    const float bz   = b_ih[32 + j] + b_hh[32 + j];
    const float bni  = b_ih[64 + j];
    const float bnh  = b_hh[64 + j];

    const float* xrow = x + (size_t)b * (size_t)T;
    const int nchunk  = T >> 6;   // 64-step chunks (T=2048 -> 32)

    float h = 0.0f;
    h_s[j] = 0.0f;                       // both halves write same value: ok
    x_s[0][l] = xrow[l];
    float xnext = (nchunk > 1) ? xrow[64 + l] : 0.0f;
    __builtin_amdgcn_wave_barrier();

    const float4* h4 = (const float4*)(h_s + half * 16);

    for (int c = 0; c < nchunk; ++c) {
        const int buf = c & 1;
        const float* xs = &x_s[buf][0];
#pragma unroll 4
        for (int s = 0; s < 64; ++s) {
            const float xv = xs[s];                  // LDS broadcast
            const float4 h0 = h4[0], h1 = h4[1], h2 = h4[2], h3 = h4[3];
            // two 8-deep chains per gate
            float ra0 =      h0.x * wr0.x;
            float za0 =      h0.x * wz0.x;
            float na0 =      h0.x * wn0.x;
            float ra1 =      h2.x * wr2.x;
            float za1 =      h2.x * wz2.x;
            float na1 =      h2.x * wn2.x;
            ra0 = fmaf(h0.y, wr0.y, ra0); za0 = fmaf(h0.y, wz0.y, za0); na0 = fmaf(h0.y, wn0.y, na0);
            ra1 = fmaf(h2.y, wr2.y, ra1); za1 = fmaf(h2.y, wz2.y, za1); na1 = fmaf(h2.y, wn2.y, na1);
            ra0 = fmaf(h0.z, wr0.z, ra0); za0 = fmaf(h0.z, wz0.z, za0); na0 = fmaf(h0.z, wn0.z, na0);
            ra1 = fmaf(h2.z, wr2.z, ra1); za1 = fmaf(h2.z, wz2.z, za1); na1 = fmaf(h2.z, wn2.z, na1);
            ra0 = fmaf(h0.w, wr0.w, ra0); za0 = fmaf(h0.w, wz0.w, za0); na0 = fmaf(h0.w, wn0.w, na0);
            ra1 = fmaf(h2.w, wr2.w, ra1); za1 = fmaf(h2.w, wz2.w, za1); na1 = fmaf(h2.w, wn2.w, na1);
            ra0 = fmaf(h1.x, wr1.x, ra0); za0 = fmaf(h1.x, wz1.x, za0); na0 = fmaf(h1.x, wn1.x, na0);
            ra1 = fmaf(h3.x, wr3.x, ra1); za1 = fmaf(h3.x, wz3.x, za1); na1 = fmaf(h3.x, wn3.x, na1);
            ra0 = fmaf(h1.y, wr1.y, ra0); za0 = fmaf(h1.y, wz1.y, za0); na0 = fmaf(h1.y, wn1.y, na0);
            ra1 = fmaf(h3.y, wr3.y, ra1); za1 = fmaf(h3.y, wz3.y, za1); na1 = fmaf(h3.y, wn3.y, na1);
            ra0 = fmaf(h1.z, wr1.z, ra0); za0 = fmaf(h1.z, wz1.z, za0); na0 = fmaf(h1.z, wn1.z, na0);
            ra1 = fmaf(h3.z, wr3.z, ra1); za1 = fmaf(h3.z, wz3.z, za1); na1 = fmaf(h3.z, wn3.z, na1);
            ra0 = fmaf(h1.w, wr1.w, ra0); za0 = fmaf(h1.w, wz1.w, za0); na0 = fmaf(h1.w, wn1.w, na0);
            ra1 = fmaf(h3.w, wr3.w, ra1); za1 = fmaf(h3.w, wz3.w, za1); na1 = fmaf(h3.w, wn3.w, na1);

            // combine halves: p + other-half p (commutative -> bitwise equal)
            float rp = ra0 + ra1;
            float zp = za0 + za1;
            float np = na0 + na1;
            rp += __shfl_xor(rp, 32, 64);
            zp += __shfl_xor(zp, 32, 64);
            np += __shfl_xor(np, 32, 64);

            const float r  = sigmoid_fast(fmaf(xv, wihr, rp + br));
            const float z  = sigmoid_fast(fmaf(xv, wihz, zp + bz));
            const float xn = fmaf(xv, wihn, bni);
            const float n  = tanh_fast(fmaf(r, np + bnh, xn));
            h = fmaf(z, h - n, n);                  // (1-z)*n + z*h
            __builtin_amdgcn_wave_barrier();
            h_s[j] = h;                             // both halves, same value
            __builtin_amdgcn_wave_barrier();        // in-order DS => RAW safe
        }
        if (c + 1 < nchunk) {
            x_s[1 - buf][l] = xnext;
            if (c + 2 < nchunk) xnext = xrow[(c + 2) * 64 + l];
            __builtin_amdgcn_wave_barrier();
        }
    }

    // ---- head: out[b,o] = head_b[o] + sum_k h[k]*head_w[o,k], o in {0,1} ----
    __builtin_amdgcn_wave_barrier();
    if (l < 2) {
        float acc = head_b[l];
        const float* hw = head_w + l * 32;
#pragma unroll
        for (int k = 0; k < 32; ++k) acc = fmaf(h_s[k], hw[k], acc);
        out[b * 2 + l] = acc;
    }
}

extern "C" void kernel_launch(void* const* d_in, const int* in_sizes, int n_in,
                              void* d_out, int out_size, void* d_ws, size_t ws_size,
                              hipStream_t stream) {
    const float* x      = (const float*)d_in[0];
    const float* w_ih   = (const float*)d_in[1];
    const float* w_hh   = (const float*)d_in[2];
    const float* b_ih   = (const float*)d_in[3];
    const float* b_hh   = (const float*)d_in[4];
    const float* head_w = (const float*)d_in[5];
    const float* head_b = (const float*)d_in[6];
    float* out = (float*)d_out;

    const int B = out_size / 2;          // O = 2
    const int T = in_sizes[0] / B;       // x is [B,T]

    dim3 grid(B), block(64);
    hipLaunchKernelGGL(gru_scan_kernel, grid, block, 0, stream,
                       x, w_ih, w_hh, b_ih, b_hh, head_w, head_b, out, T);
}

// Round 3
// 611.556 us; speedup vs baseline: 1.1874x; 1.1874x over previous
//
#include <hip/hip_runtime.h>

// SimpleGRU scan: B=2048 seqs, T=2048 steps, H=32, O=2, fp32.
// Round-3: round-1 layout (32 lanes/batch, 2 batches/wave, grid 1024,
// 1 wave/SIMD) with two fixes driven by rocprof evidence:
//  (a) VGPR_Count was 68/48 in rounds 1/2 -> weight loads were sunk into the
//      K-loop by the backend (per-step L1 reloads). Fix: opaque asm pin of
//      all 96 per-lane weights -> forced VGPR residency.
//  (b) round 1 used one 32-deep FMA chain (128 cyc serial). Fix: 4 chains of
//      8 per gate + pairwise combine (~40 cyc).
// Per step: 8x ds_read_b128 h broadcast (conflict-free) + 96 FMA + exp/rcp
// activations + 1 ds_write. Within-wave LDS RAW relies on in-order DS pipe;
// wave_barrier() pins compiler ordering (single wave per block).

__device__ __forceinline__ float sigmoid_fast(float s) {
    float e = __builtin_amdgcn_exp2f(s * -1.44269504088896340736f);
    return __builtin_amdgcn_rcpf(1.0f + e);
}

__device__ __forceinline__ float tanh_fast(float u) {
    // tanh(u) = 1 - 2/(1+exp2(2*log2e*u)); robust in fp32 at both tails
    float e = __builtin_amdgcn_exp2f(u * 2.88539008177792681472f);
    float r = __builtin_amdgcn_rcpf(1.0f + e);
    return fmaf(-2.0f, r, 1.0f);
}

__global__ __launch_bounds__(64, 1)
void gru_scan_kernel(const float* __restrict__ x,      // [B,T]
                     const float* __restrict__ w_ih,   // [96,1]
                     const float* __restrict__ w_hh,   // [96,32]
                     const float* __restrict__ b_ih,   // [96]
                     const float* __restrict__ b_hh,   // [96]
                     const float* __restrict__ head_w, // [2,32]
                     const float* __restrict__ head_b, // [2]
                     float* __restrict__ out,          // [B,2]
                     int T)
{
    const int tid = (int)threadIdx.x;
    const int g   = tid >> 5;   // batch slot within wave (0,1)
    const int j   = tid & 31;   // hidden/gate index
    const int b   = (int)blockIdx.x * 2 + g;

    // pad to 36 floats: group1's quad-q read hits banks {4q+4..4q+7} vs
    // group0 {4q..4q+3} (mod 32) -> disjoint, conflict-free broadcast.
    __shared__ __align__(16) float h_s[2][36];
    __shared__ __align__(16) float x_s[2][2][32];  // [group][buf][step]

    // ---- per-lane recurrent weights: rows j (r), 32+j (z), 64+j (n) ----
    float wr[32], wz[32], wn[32];
    {
        const float4* wr4 = (const float4*)(w_hh + (j     ) * 32);
        const float4* wz4 = (const float4*)(w_hh + (32 + j) * 32);
        const float4* wn4 = (const float4*)(w_hh + (64 + j) * 32);
#pragma unroll
        for (int q = 0; q < 8; ++q) {
            float4 a = wr4[q];
            wr[4*q+0]=a.x; wr[4*q+1]=a.y; wr[4*q+2]=a.z; wr[4*q+3]=a.w;
            float4 c = wz4[q];
            wz[4*q+0]=c.x; wz[4*q+1]=c.y; wz[4*q+2]=c.z; wz[4*q+3]=c.w;
            float4 d = wn4[q];
            wn[4*q+0]=d.x; wn[4*q+1]=d.y; wn[4*q+2]=d.z; wn[4*q+3]=d.w;
        }
    }
    // Opaque pin: each weight's only reaching def is this asm -> the
    // scheduler cannot sink/rematerialize the loads into the T-loop.
#pragma unroll
    for (int k = 0; k < 32; ++k) {
        asm volatile("" : "+v"(wr[k]), "+v"(wz[k]), "+v"(wn[k]));
    }

    const float wihr = w_ih[j];
    const float wihz = w_ih[32 + j];
    const float wihn = w_ih[64 + j];
    const float br   = b_ih[j]      + b_hh[j];
    const float bz   = b_ih[32 + j] + b_hh[32 + j];
    const float bni  = b_ih[64 + j];
    const float bnh  = b_hh[64 + j];

    const float* xrow   = x + (size_t)b * (size_t)T;
    const int    nchunk = T >> 5;   // 32-step chunks (T=2048 -> 64)

    float h = 0.0f;
    h_s[g][j]    = 0.0f;
    x_s[g][0][j] = xrow[j];
    float xnext  = (nchunk > 1) ? xrow[32 + j] : 0.0f;
    __builtin_amdgcn_wave_barrier();

    const float4* h4 = (const float4*)(&h_s[g][0]);

    for (int c = 0; c < nchunk; ++c) {
        const int buf = c & 1;
        const float* xs = &x_s[g][buf][0];
#pragma unroll 2
        for (int s = 0; s < 32; ++s) {
            const float xv = xs[s];                 // LDS broadcast
            const float4 h0 = h4[0], h1 = h4[1], h2 = h4[2], h3 = h4[3];
            const float4 h4q = h4[4], h5 = h4[5], h6 = h4[6], h7 = h4[7];

            // 4 chains of 8 per gate; chain0 seeded with x-gate + bias
            float r0 = fmaf(xv, wihr, br);
            float z0 = fmaf(xv, wihz, bz);
            float n0 = bnh;
            r0 = fmaf(h0.x, wr[ 0], r0); z0 = fmaf(h0.x, wz[ 0], z0); n0 = fmaf(h0.x, wn[ 0], n0);
            r0 = fmaf(h0.y, wr[ 1], r0); z0 = fmaf(h0.y, wz[ 1], z0); n0 = fmaf(h0.y, wn[ 1], n0);
            r0 = fmaf(h0.z, wr[ 2], r0); z0 = fmaf(h0.z, wz[ 2], z0); n0 = fmaf(h0.z, wn[ 2], n0);
            r0 = fmaf(h0.w, wr[ 3], r0); z0 = fmaf(h0.w, wz[ 3], z0); n0 = fmaf(h0.w, wn[ 3], n0);
            r0 = fmaf(h1.x, wr[ 4], r0); z0 = fmaf(h1.x, wz[ 4], z0); n0 = fmaf(h1.x, wn[ 4], n0);
            r0 = fmaf(h1.y, wr[ 5], r0); z0 = fmaf(h1.y, wz[ 5], z0); n0 = fmaf(h1.y, wn[ 5], n0);
            r0 = fmaf(h1.z, wr[ 6], r0); z0 = fmaf(h1.z, wz[ 6], z0); n0 = fmaf(h1.z, wn[ 6], n0);
            r0 = fmaf(h1.w, wr[ 7], r0); z0 = fmaf(h1.w, wz[ 7], z0); n0 = fmaf(h1.w, wn[ 7], n0);

            float r1 = h2.x * wr[ 8], z1 = h2.x * wz[ 8], n1 = h2.x * wn[ 8];
            r1 = fmaf(h2.y, wr[ 9], r1); z1 = fmaf(h2.y, wz[ 9], z1); n1 = fmaf(h2.y, wn[ 9], n1);
            r1 = fmaf(h2.z, wr[10], r1); z1 = fmaf(h2.z, wz[10], z1); n1 = fmaf(h2.z, wn[10], n1);
            r1 = fmaf(h2.w, wr[11], r1); z1 = fmaf(h2.w, wz[11], z1); n1 = fmaf(h2.w, wn[11], n1);
            r1 = fmaf(h3.x, wr[12], r1); z1 = fmaf(h3.x, wz[12], z1); n1 = fmaf(h3.x, wn[12], n1);
            r1 = fmaf(h3.y, wr[13], r1); z1 = fmaf(h3.y, wz[13], z1); n1 = fmaf(h3.y, wn[13], n1);
            r1 = fmaf(h3.z, wr[14], r1); z1 = fmaf(h3.z, wz[14], z1); n1 = fmaf(h3.z, wn[14], n1);
            r1 = fmaf(h3.w, wr[15], r1); z1 = fmaf(h3.w, wz[15], z1); n1 = fmaf(h3.w, wn[15], n1);

            float r2 = h4q.x * wr[16], z2 = h4q.x * wz[16], n2 = h4q.x * wn[16];
            r2 = fmaf(h4q.y, wr[17], r2); z2 = fmaf(h4q.y, wz[17], z2); n2 = fmaf(h4q.y, wn[17], n2);
            r2 = fmaf(h4q.z, wr[18], r2); z2 = fmaf(h4q.z, wz[18], z2); n2 = fmaf(h4q.z, wn[18], n2);
            r2 = fmaf(h4q.w, wr[19], r2); z2 = fmaf(h4q.w, wz[19], z2); n2 = fmaf(h4q.w, wn[19], n2);
            r2 = fmaf(h5.x,  wr[20], r2); z2 = fmaf(h5.x,  wz[20], z2); n2 = fmaf(h5.x,  wn[20], n2);
            r2 = fmaf(h5.y,  wr[21], r2); z2 = fmaf(h5.y,  wz[21], z2); n2 = fmaf(h5.y,  wn[21], n2);
            r2 = fmaf(h5.z,  wr[22], r2); z2 = fmaf(h5.z,  wz[22], z2); n2 = fmaf(h5.z,  wn[22], n2);
            r2 = fmaf(h5.w,  wr[23], r2); z2 = fmaf(h5.w,  wz[23], z2); n2 = fmaf(h5.w,  wn[23], n2);

            float r3 = h6.x * wr[24], z3 = h6.x * wz[24], n3 = h6.x * wn[24];
            r3 = fmaf(h6.y, wr[25], r3); z3 = fmaf(h6.y, wz[25], z3); n3 = fmaf(h6.y, wn[25], n3);
            r3 = fmaf(h6.z, wr[26], r3); z3 = fmaf(h6.z, wz[26], z3); n3 = fmaf(h6.z, wn[26], n3);
            r3 = fmaf(h6.w, wr[27], r3); z3 = fmaf(h6.w, wz[27], z3); n3 = fmaf(h6.w, wn[27], n3);
            r3 = fmaf(h7.x, wr[28], r3); z3 = fmaf(h7.x, wz[28], z3); n3 = fmaf(h7.x, wn[28], n3);
            r3 = fmaf(h7.y, wr[29], r3); z3 = fmaf(h7.y, wz[29], z3); n3 = fmaf(h7.y, wn[29], n3);
            r3 = fmaf(h7.z, wr[30], r3); z3 = fmaf(h7.z, wz[30], z3); n3 = fmaf(h7.z, wn[30], n3);
            r3 = fmaf(h7.w, wr[31], r3); z3 = fmaf(h7.w, wz[31], z3); n3 = fmaf(h7.w, wn[31], n3);

            const float r  = sigmoid_fast((r0 + r1) + (r2 + r3));
            const float z  = sigmoid_fast((z0 + z1) + (z2 + z3));
            const float xn = fmaf(xv, wihn, bni);
            const float n  = tanh_fast(fmaf(r, (n0 + n1) + (n2 + n3), xn));
            h = fmaf(z, h - n, n);                  // (1-z)*n + z*h
            __builtin_amdgcn_wave_barrier();
            h_s[g][j] = h;                          // publish for next step
            __builtin_amdgcn_wave_barrier();        // in-order DS => RAW safe
        }
        if (c + 1 < nchunk) {
            x_s[g][1 - buf][j] = xnext;             // stage next chunk
            if (c + 2 < nchunk) xnext = xrow[(c + 2) * 32 + j];
            __builtin_amdgcn_wave_barrier();
        }
    }

    // ---- head: out[b,o] = head_b[o] + sum_k h[k]*head_w[o,k], o in {0,1} ----
    __builtin_amdgcn_wave_barrier();
    if (j < 2) {
        float acc = head_b[j];
        const float* hw = head_w + j * 32;
#pragma unroll
        for (int k = 0; k < 32; ++k) acc = fmaf(h_s[g][k], hw[k], acc);
        out[b * 2 + j] = acc;
    }
}

extern "C" void kernel_launch(void* const* d_in, const int* in_sizes, int n_in,
                              void* d_out, int out_size, void* d_ws, size_t ws_size,
                              hipStream_t stream) {
    const float* x      = (const float*)d_in[0];
    const float* w_ih   = (const float*)d_in[1];
    const float* w_hh   = (const float*)d_in[2];
    const float* b_ih   = (const float*)d_in[3];
    const float* b_hh   = (const float*)d_in[4];
    const float* head_w = (const float*)d_in[5];
    const float* head_b = (const float*)d_in[6];
    float* out = (float*)d_out;

    const int B = out_size / 2;          // O = 2
    const int T = in_sizes[0] / B;       // x is [B,T]

    dim3 grid(B / 2), block(64);
    hipLaunchKernelGGL(gru_scan_kernel, grid, block, 0, stream,
                       x, w_ih, w_hh, b_ih, b_hh, head_w, head_b, out, T);
}